// Round 1
// baseline (364.235 us; speedup 1.0000x reference)
//
#include <hip/hip_runtime.h>

// SobelLoss: loss = valid * (|Sx (x) (pred-tgt)| + |Sy (x) (pred-tgt)|)
// Shapes: (B=2,T=6,H=512,W=512,F=8), layout row-major with F innermost.
// valid(h,w,f) = AND of mask over 3x3 neighborhood; zero-padded => border
// outputs are always 0 (no bounds checks needed for interior loads).

constexpr int H = 512;
constexpr int W = 512;
constexpr int F = 8;
constexpr int IMAGES = 12;              // B*T
constexpr int ROWSTRIDE = W * F;        // elements per image row
constexpr int TILES_PER_IMG = (H / 16) * (W / 16);  // 1024

__global__ __launch_bounds__(256) void sobel_loss_kernel(
    const float* __restrict__ pred,
    const float* __restrict__ tgt,
    const int*   __restrict__ mask,
    float*       __restrict__ out)
{
    const int tid = threadIdx.x;
    const int tw  = tid & 15;
    const int th  = tid >> 4;

    int bid = blockIdx.x;
    const int img  = bid / TILES_PER_IMG;
    const int tile = bid - img * TILES_PER_IMG;
    const int h = ((tile >> 5) << 4) + th;   // (tile / 32) * 16 + th
    const int w = ((tile & 31) << 4) + tw;   // (tile % 32) * 16 + tw

    const int pos = img * (H * W * F) + (h * W + w) * F;

    if (h == 0 || h == H - 1 || w == 0 || w == W - 1) {
        // Border: valid mask can never reach 9 under zero padding.
        *(float4*)(out + pos)     = make_float4(0.f, 0.f, 0.f, 0.f);
        *(float4*)(out + pos + 4) = make_float4(0.f, 0.f, 0.f, 0.f);
        return;
    }

#pragma unroll
    for (int q = 0; q < 2; ++q) {
        const int p0 = pos + q * 4;

        float4 d[3][3];
        int4 mv = make_int4(1, 1, 1, 1);

#pragma unroll
        for (int i = 0; i < 3; ++i) {
#pragma unroll
            for (int j = 0; j < 3; ++j) {
                const int o = p0 + (i - 1) * ROWSTRIDE + (j - 1) * F;
                const float4 p = *(const float4*)(pred + o);
                const float4 t = *(const float4*)(tgt + o);
                d[i][j] = make_float4(p.x - t.x, p.y - t.y, p.z - t.z, p.w - t.w);
                const int4 m = *(const int4*)(mask + o);
                mv.x &= m.x; mv.y &= m.y; mv.z &= m.z; mv.w &= m.w;
            }
        }

        float4 r;
#define SOBEL_COMP(c)                                                          \
        {                                                                      \
            float gx = (d[0][2].c - d[0][0].c)                                 \
                     + 2.f * (d[1][2].c - d[1][0].c)                           \
                     + (d[2][2].c - d[2][0].c);                                \
            float gy = (d[2][0].c - d[0][0].c)                                 \
                     + 2.f * (d[2][1].c - d[0][1].c)                           \
                     + (d[2][2].c - d[0][2].c);                                \
            r.c = (mv.c != 0) ? (fabsf(gx) + fabsf(gy)) : 0.f;                 \
        }
        SOBEL_COMP(x)
        SOBEL_COMP(y)
        SOBEL_COMP(z)
        SOBEL_COMP(w)
#undef SOBEL_COMP

        *(float4*)(out + p0) = r;
    }
}

extern "C" void kernel_launch(void* const* d_in, const int* in_sizes, int n_in,
                              void* d_out, int out_size, void* d_ws, size_t ws_size,
                              hipStream_t stream) {
    const float* pred = (const float*)d_in[0];
    const float* tgt  = (const float*)d_in[1];
    const int*   mask = (const int*)d_in[2];
    float*       out  = (float*)d_out;

    const int blocks = IMAGES * TILES_PER_IMG;  // 12288
    sobel_loss_kernel<<<blocks, 256, 0, stream>>>(pred, tgt, mask, out);
}

// Round 2
// 302.874 us; speedup vs baseline: 1.2026x; 1.2026x over previous
//
#include <hip/hip_runtime.h>

// SobelLoss: loss = valid * (|Sx (x) (pred-tgt)| + |Sy (x) (pred-tgt)|)
// Shapes: (B=2,T=6,H=512,W=512,F=8), fp32, F innermost.
// valid(h,w,f) = AND of mask over 3x3 neighborhood (zero-padded => border = 0).
//
// R2 design: LDS-staged stencil. Block = 16 rows x 32 pixels tile.
// Stage d = pred - tgt (float4 per (pixel,q)) and bit-packed mask (8 lanes ->
// low 8 bits of a uint per pixel) for the 18x34 halo region; one global touch
// per element. Compute phase reads the 3x3 neighborhood from LDS.
// R1 was latency-bound (54 global loads/thread, VALUBusy 7%, HBM 23%).

constexpr int H = 512;
constexpr int W = 512;
constexpr int F = 8;
constexpr int IMAGES = 12;          // B*T
constexpr int TH = 16;              // tile height (output rows)
constexpr int TWP = 32;             // tile width in pixels
constexpr int SR = TH + 2;          // staged rows (18)
constexpr int SP = TWP + 2;         // staged pixels per row (34)
constexpr int SU = SP * 2;          // staged float4 units per row (68)
constexpr int TILES_PER_IMG = (H / TH) * (W / TWP);  // 32*16 = 512

__global__ __launch_bounds__(256) void sobel_loss_kernel(
    const float* __restrict__ pred,
    const float* __restrict__ tgt,
    const int*   __restrict__ mask,
    float*       __restrict__ out)
{
    __shared__ float4   sd[SR * SU];      // 18*68*16B = 19584 B
    __shared__ unsigned sm[SR * SP];      // 18*34*4B  =  2448 B

    const int tid = threadIdx.x;
    const int img  = blockIdx.x >> 9;            // / 512
    const int tile = blockIdx.x & 511;
    const int h0 = (tile >> 4) << 4;             // (tile/16)*16
    const int w0 = (tile & 15) << 5;             // (tile%16)*32
    const size_t ibase = (size_t)img * (H * W * F);

    // ---- Stage d = pred - tgt (one float4 unit per staged (pixel,q)) ----
#pragma unroll
    for (int it = 0; it < 5; ++it) {
        const int s = tid + it * 256;
        if (s < SR * SU) {
            const int row = s / SU;
            const int u   = s - row * SU;
            const int gh  = h0 - 1 + row;
            const int gp  = w0 - 1 + (u >> 1);
            const int q   = u & 1;
            // Clamp addresses (OOB values are harmless: mask forces border=0)
            const int ghc = min(max(gh, 0), H - 1);
            const int gpc = min(max(gp, 0), W - 1);
            const size_t off = ibase + ((size_t)ghc * W + gpc) * F + q * 4;
            const float4 p = *(const float4*)(pred + off);
            const float4 t = *(const float4*)(tgt + off);
            sd[s] = make_float4(p.x - t.x, p.y - t.y, p.z - t.z, p.w - t.w);
        }
    }

    // ---- Stage bit-packed mask: one uint per staged pixel (8 lane bits) ----
#pragma unroll
    for (int it = 0; it < 3; ++it) {
        const int s = tid + it * 256;
        if (s < SR * SP) {
            const int row = s / SP;
            const int px  = s - row * SP;
            const int gh  = h0 - 1 + row;
            const int gp  = w0 - 1 + px;
            unsigned b = 0u;
            if (gh >= 0 && gh < H && gp >= 0 && gp < W) {
                const int* mp = mask + ibase + ((size_t)gh * W + gp) * F;
                const int4 m0 = *(const int4*)mp;
                const int4 m1 = *(const int4*)(mp + 4);
                // mask values are 0/1 ints
                b = (unsigned)(m0.x | (m0.y << 1) | (m0.z << 2) | (m0.w << 3) |
                               (m1.x << 4) | (m1.y << 5) | (m1.z << 6) | (m1.w << 7));
            }
            sm[s] = b;
        }
    }

    __syncthreads();

    // ---- Compute: 4 output units per thread ----
#pragma unroll
    for (int it = 0; it < 4; ++it) {
        const int o   = tid + it * 256;          // 0..1023
        const int row = o >> 6;                  // output row in tile
        const int u   = o & 63;
        const int c   = u >> 1;                  // output pixel in tile
        const int q   = u & 1;

        float4 d[3][3];
        unsigned vm = 0xFFu;
#pragma unroll
        for (int dy = 0; dy < 3; ++dy) {
#pragma unroll
            for (int dx = 0; dx < 3; ++dx) {
                d[dy][dx] = sd[(row + dy) * SU + (c + dx) * 2 + q];
                vm &= sm[(row + dy) * SP + (c + dx)];
            }
        }
        const unsigned vq = vm >> (q * 4);

        float4 r;
#define SOBEL_COMP(comp, bit)                                                  \
        {                                                                      \
            float gx = (d[0][2].comp - d[0][0].comp)                           \
                     + 2.f * (d[1][2].comp - d[1][0].comp)                     \
                     + (d[2][2].comp - d[2][0].comp);                          \
            float gy = (d[2][0].comp - d[0][0].comp)                           \
                     + 2.f * (d[2][1].comp - d[0][1].comp)                     \
                     + (d[2][2].comp - d[0][2].comp);                          \
            r.comp = (vq & (1u << bit)) ? (fabsf(gx) + fabsf(gy)) : 0.f;       \
        }
        SOBEL_COMP(x, 0)
        SOBEL_COMP(y, 1)
        SOBEL_COMP(z, 2)
        SOBEL_COMP(w, 3)
#undef SOBEL_COMP

        const size_t off = ibase + ((size_t)(h0 + row) * W + (w0 + c)) * F + q * 4;
        *(float4*)(out + off) = r;
    }
}

extern "C" void kernel_launch(void* const* d_in, const int* in_sizes, int n_in,
                              void* d_out, int out_size, void* d_ws, size_t ws_size,
                              hipStream_t stream) {
    const float* pred = (const float*)d_in[0];
    const float* tgt  = (const float*)d_in[1];
    const int*   mask = (const int*)d_in[2];
    float*       out  = (float*)d_out;

    const int blocks = IMAGES * TILES_PER_IMG;  // 6144
    sobel_loss_kernel<<<blocks, 256, 0, stream>>>(pred, tgt, mask, out);
}